// Round 17
// baseline (256.980 us; speedup 1.0000x reference)
//
#include <hip/hip_runtime.h>
#include <hip/hip_bf16.h>

#define B_  2
#define S_  2048
#define H_  24
#define DH_ 32
#define E_  768
#define SW_ (S_/32)   // mask words per row = 64

#define NB_QKV  ((S_/64)*(B_*H_))      // 1536 blocks (qkv part, dispatched first)
#define NB_MASK ((B_*S_*S_)/256)       // 32768 blocks
#define NB_WO   ((E_*E_)/1024)         // 576 blocks

typedef __attribute__((ext_vector_type(8))) short short8;   // 8 x bf16 bits
typedef __attribute__((ext_vector_type(4))) float f32x4;
typedef _Float16 half8  __attribute__((ext_vector_type(8)));
typedef _Float16 half2v __attribute__((ext_vector_type(2)));
typedef __fp16   fp16x2 __attribute__((ext_vector_type(2)));   // cvt_pkrtz return type

// fp32 pair -> packed fp16 (one v_cvt_pkrtz_f16_f32), as _Float16 vector
static __device__ __forceinline__ half2v cvt2h(float a, float b) {
    fp16x2 t = __builtin_amdgcn_cvt_pkrtz(a, b);
    return __builtin_bit_cast(half2v, t);
}

// 4 floats -> 4 bf16 packed in 8B
static __device__ __forceinline__ short4 pack4(float a, float b, float c, float d) {
    union { __hip_bfloat162 h[2]; short4 s; } u;
    u.h[0] = __float22bfloat162_rn(make_float2(a, b));
    u.h[1] = __float22bfloat162_rn(make_float2(c, d));
    return u.s;
}
static __device__ __forceinline__ short8 pack8f(const float* a, const float* b) {
    union { __hip_bfloat162 h[4]; short8 s; } u;
    u.h[0] = __float22bfloat162_rn(make_float2(a[0], a[1]));
    u.h[1] = __float22bfloat162_rn(make_float2(a[2], a[3]));
    u.h[2] = __float22bfloat162_rn(make_float2(b[0], b[1]));
    u.h[3] = __float22bfloat162_rn(make_float2(b[2], b[3]));
    return u.s;
}
static __device__ __forceinline__ short8 pack8(float4 a, float4 b) {
    union { __hip_bfloat162 h[4]; short8 s; } u;
    u.h[0] = __float22bfloat162_rn(make_float2(a.x, a.y));
    u.h[1] = __float22bfloat162_rn(make_float2(a.z, a.w));
    u.h[2] = __float22bfloat162_rn(make_float2(b.x, b.y));
    u.h[3] = __float22bfloat162_rn(make_float2(b.z, b.w));
    return u.s;
}
// weight fragment straight from fp32 W[h-base][d][e]: F[j] = W[(quad*8+j)*32+eo]
static __device__ __forceinline__ short8 wfrag(const float* __restrict__ Wb,
                                               int quad, int eo) {
    float w[8];
#pragma unroll
    for (int j = 0; j < 8; ++j) w[j] = Wb[(quad * 8 + j) * 32 + eo];
    return pack8f(w, w + 4);
}

// Q pre-scaled by (1/sqrt(32))*log2(e): MFMA scores land in the exp2 domain.
// Masked branch selects x=0 BEFORE the poly; poly(0) = 1.0 exactly.
#define QSCALE  0.25503487f

// ---------------------------------------------------------------------------
// Kernel 0: FUSED prep + qkv (mutually independent parts, one launch).
// ---------------------------------------------------------------------------
__global__ __launch_bounds__(256) void prep_qkv_kernel(
    const float* __restrict__ x, const int* __restrict__ mask,
    const float* __restrict__ Wo,
    const float* __restrict__ Wq, const float* __restrict__ Wk,
    const float* __restrict__ Wv,
    __hip_bfloat16* __restrict__ Qo,
    __hip_bfloat16* __restrict__ Ko,      // permuted-key layout, bf16
    _Float16* __restrict__ Vto,           // fp16 (PV runs on f16 MFMA)
    unsigned int* __restrict__ mbits, _Float16* __restrict__ Wob)
{
    const int bx = blockIdx.x;
    if (bx < NB_QKV) {
        // ---- QKV: 16 s-rows/wave, 6 MFMAs. K stored PERMUTED within each
        // 32-key tile: key k=8q+4u+i -> slot (u<<4)|(q*4+i) so attn's score
        // MFMAs produce P directly in PV B-operand register layout. ----
        const int bh   = bx >> 5;            // [0,48)
        const int b    = bh / H_;
        const int h    = bh - b * H_;
        const int wave = threadIdx.x >> 6;
        const int lane = threadIdx.x & 63;
        const int col  = lane & 15;
        const int quad = lane >> 4;
        const int sw   = (bx & 31) * 64 + wave * 16;
        const int s    = sw + col;

        const float* xp = x + ((size_t)b * S_ + s) * E_ + h * DH_ + quad * 8;
        const float4 xa = *reinterpret_cast<const float4*>(xp);
        const float4 xb = *reinterpret_cast<const float4*>(xp + 4);
        const short8 xf = pack8(xa, xb);

        const int wb = h * DH_ * DH_;
        const short8 aQ0 = wfrag(Wq + wb, quad, col);
        const short8 aQ1 = wfrag(Wq + wb, quad, col + 16);
        const short8 aK0 = wfrag(Wk + wb, quad, col);
        const short8 aK1 = wfrag(Wk + wb, quad, col + 16);
        const short8 bV0 = wfrag(Wv + wb, quad, col);
        const short8 bV1 = wfrag(Wv + wb, quad, col + 16);

        const f32x4 z = {0.f, 0.f, 0.f, 0.f};
        const f32x4 qt0 = __builtin_amdgcn_mfma_f32_16x16x32_bf16(aQ0, xf, z, 0, 0, 0);
        const f32x4 qt1 = __builtin_amdgcn_mfma_f32_16x16x32_bf16(aQ1, xf, z, 0, 0, 0);
        const f32x4 kt0 = __builtin_amdgcn_mfma_f32_16x16x32_bf16(aK0, xf, z, 0, 0, 0);
        const f32x4 kt1 = __builtin_amdgcn_mfma_f32_16x16x32_bf16(aK1, xf, z, 0, 0, 0);
        const f32x4 vv0 = __builtin_amdgcn_mfma_f32_16x16x32_bf16(xf, bV0, z, 0, 0, 0);
        const f32x4 vv1 = __builtin_amdgcn_mfma_f32_16x16x32_bf16(xf, bV1, z, 0, 0, 0);

        __hip_bfloat16* qrow = Qo + ((size_t)bh * S_ + s) * DH_;
        *reinterpret_cast<short4*>(qrow + quad * 4) =
            pack4(qt0[0] * QSCALE, qt0[1] * QSCALE, qt0[2] * QSCALE, qt0[3] * QSCALE);
        *reinterpret_cast<short4*>(qrow + 16 + quad * 4) =
            pack4(qt1[0] * QSCALE, qt1[1] * QSCALE, qt1[2] * QSCALE, qt1[3] * QSCALE);

        const int t32  = s & 31;
        const int slot = (s & ~31) | (((t32 >> 2) & 1) << 4)
                       | (((t32 >> 3) << 2) | (t32 & 3));
        __hip_bfloat16* krow = Ko + ((size_t)bh * S_ + slot) * DH_;
        *reinterpret_cast<short4*>(krow + quad * 4)      = pack4(kt0[0], kt0[1], kt0[2], kt0[3]);
        *reinterpret_cast<short4*>(krow + 16 + quad * 4) = pack4(kt1[0], kt1[1], kt1[2], kt1[3]);

        const int sb = sw + quad * 4;
        union { half2v h[2]; uint2 u; } v0u, v1u;
        v0u.h[0] = cvt2h(vv0[0], vv0[1]); v0u.h[1] = cvt2h(vv0[2], vv0[3]);
        v1u.h[0] = cvt2h(vv1[0], vv1[1]); v1u.h[1] = cvt2h(vv1[2], vv1[3]);
        *reinterpret_cast<uint2*>(Vto + ((size_t)bh * DH_ + col) * S_ + sb)      = v0u.u;
        *reinterpret_cast<uint2*>(Vto + ((size_t)bh * DH_ + 16 + col) * S_ + sb) = v1u.u;
    } else if (bx < NB_QKV + NB_MASK) {
        const int idx  = (bx - NB_QKV) * 256 + threadIdx.x;
        const int lane = threadIdx.x & 63;
        const unsigned long long bal = __ballot(mask[idx] != 0);
        if (lane == 0) {
            uint2 w;
            w.x = (unsigned int)(bal & 0xffffffffull);
            w.y = (unsigned int)(bal >> 32);
            *reinterpret_cast<uint2*>(mbits + (idx >> 5)) = w;
        }
    } else {
        const int i = ((bx - NB_QKV - NB_MASK) * 256 + threadIdx.x) * 4;
        const float4 w = *reinterpret_cast<const float4*>(Wo + i);
        union { half2v h[2]; uint2 u; } uu;
        uu.h[0] = cvt2h(w.x, w.y);
        uu.h[1] = cvt2h(w.z, w.w);
        *reinterpret_cast<uint2*>(Wob + i) = uu.u;
    }
}

// ---------------------------------------------------------------------------
// Kernel 2: fused attention v15 — 32 q-rows/wave, 2x WAVE SUPPLY.
// R16 showed the wall is stalls with only 3 waves/SIMD (grid-limited, not
// HW-limited). Halving the per-wave q-tile doubles the wave pool
// (6144 single-wave blocks = 6/SIMD; VGPR ~75 allows 6 resident).
// Total VALU work is invariant (poly ops ~ q x k pairs); per-iter VALU
// halves, stall share shrinks. K/V loads double in issue count but stay
// L2-resident (XCD swizzle). Body otherwise = R16 (poly-exp fp16, f16 PV,
// ones-l MFMA). grid = 3072*parts, block = 64.
// ---------------------------------------------------------------------------
__global__ __launch_bounds__(64) void attn_kernel(
    const __hip_bfloat16* __restrict__ Q,     // [B*H][S][DH] (pre-scaled)
    const __hip_bfloat16* __restrict__ K,     // [B*H][S][DH] permuted tiles
    const _Float16* __restrict__ Vt,          // [B*H][DH][S] fp16
    const unsigned int* __restrict__ mbits,   // [B][S][S/32]
    _Float16* __restrict__ Opart,             // [parts][B][S][E] unnormalized
    float* __restrict__ lpart,                // [parts][B*H][S]
    int parts)
{
    // XCD-aware decode: bid%8 = XCD; each XCD owns 6 heads.
    const int bid  = blockIdx.x;
    const int xcd  = bid & 7;
    const int t_   = bid >> 3;                 // [0, 6*64*parts)
    const int bh   = xcd * 6 + (t_ % 6);
    const int rest = t_ / 6;                   // [0, 64*parts)
    const int qsub = rest & 63;                // 32-row chunk index
    const int part = rest >> 6;                // [0, parts)

    const int b    = bh / H_;
    const int h    = bh - b * H_;
    const int niter = S_ / (64 * parts);
    const int kbeg  = part * (S_ / parts);
    const int lane = threadIdx.x & 63;
    const int col  = lane & 15;
    const int quad = lane >> 4;
    const int q0   = qsub * 32;

    const __hip_bfloat16* Qbh = Q  + (size_t)bh * S_ * DH_;
    const __hip_bfloat16* Kbh = K  + (size_t)bh * S_ * DH_;
    const _Float16*       Vbh = Vt + (size_t)bh * DH_ * S_;

    short8 qf[2];
#pragma unroll
    for (int t = 0; t < 2; ++t)
        qf[t] = *reinterpret_cast<const short8*>(
            Qbh + (size_t)(q0 + t * 16 + col) * DH_ + quad * 8);

    const __hip_bfloat16* Kp  = Kbh + (size_t)(kbeg + col) * DH_ + quad * 8;
    const _Float16*       Vp0 = Vbh + (size_t)col * S_ + kbeg + quad * 8;
    const _Float16*       Vp1 = Vbh + (size_t)(16 + col) * S_ + kbeg + quad * 8;
    const unsigned int* mbb = mbits + (size_t)b * S_ * SW_ + (kbeg >> 5);
    const unsigned int* mp[2];
#pragma unroll
    for (int t = 0; t < 2; ++t)
        mp[t] = mbb + (size_t)(q0 + t * 16 + col) * SW_;

    // per-lane AND-bitmasks
    unsigned bitL[4], bitH[4];
#pragma unroll
    for (int r = 0; r < 4; ++r) {
        bitL[r] = 1u << (quad * 8 + r);
        bitH[r] = 1u << (quad * 8 + 4 + r);
    }

    // 2^x Taylor-4 coefficients, packed fp16
    const half2v C4 = cvt2h(0.0096181f, 0.0096181f);
    const half2v C3 = cvt2h(0.0555041f, 0.0555041f);
    const half2v C2 = cvt2h(0.2402265f, 0.2402265f);
    const half2v C1 = cvt2h(0.6931472f, 0.6931472f);
    const half2v C0 = cvt2h(1.0f, 1.0f);

    union { uint4 u; half8 v; } onesu;
    onesu.u = make_uint4(0x3C003C00u, 0x3C003C00u, 0x3C003C00u, 0x3C003C00u);
    const half8 ones_h = onesu.v;

    f32x4 o0a[2], o1a[2], la[2];
#pragma unroll
    for (int t = 0; t < 2; ++t) {
        o0a[t] = (f32x4){0.f,0.f,0.f,0.f};
        o1a[t] = (f32x4){0.f,0.f,0.f,0.f};
        la[t]  = (f32x4){0.f,0.f,0.f,0.f};
    }

    for (int it = 0; it < niter; ++it) {
        uint2 mw[2];
#pragma unroll
        for (int t = 0; t < 2; ++t)
            mw[t] = *reinterpret_cast<const uint2*>(mp[t]);

        const short8 kA0 = *reinterpret_cast<const short8*>(Kp);
        const short8 kA1 = *reinterpret_cast<const short8*>(Kp + 16 * DH_);
        const half8  vA0 = *reinterpret_cast<const half8*>(Vp0);
        const half8  vA1 = *reinterpret_cast<const half8*>(Vp1);
        const short8 kB0 = *reinterpret_cast<const short8*>(Kp + 32 * DH_);
        const short8 kB1 = *reinterpret_cast<const short8*>(Kp + 48 * DH_);
        const half8  vB0 = *reinterpret_cast<const half8*>(Vp0 + 32);
        const half8  vB1 = *reinterpret_cast<const half8*>(Vp1 + 32);

        const f32x4 z = {0.f, 0.f, 0.f, 0.f};

        // ---- subtile A (keys +0..31) ----
        f32x4 s0[2], s1[2];
#pragma unroll
        for (int t = 0; t < 2; ++t) {
            s0[t] = __builtin_amdgcn_mfma_f32_16x16x32_bf16(kA0, qf[t], z, 0, 0, 0);
            s1[t] = __builtin_amdgcn_mfma_f32_16x16x32_bf16(kA1, qf[t], z, 0, 0, 0);
        }
#pragma unroll
        for (int t = 0; t < 2; ++t) {
            float x0[4], x1[4];
#pragma unroll
            for (int r = 0; r < 4; ++r) {
                x0[r] = (mw[t].x & bitL[r]) ? s0[t][r] : 0.0f;
                x1[r] = (mw[t].x & bitH[r]) ? s1[t][r] : 0.0f;
            }
            union { half2v h[4]; half8 v; } pu;
#pragma unroll
            for (int pr = 0; pr < 4; ++pr) {
                const half2v xx = (pr < 2) ? cvt2h(x0[pr * 2], x0[pr * 2 + 1])
                                           : cvt2h(x1[(pr - 2) * 2], x1[(pr - 2) * 2 + 1]);
                half2v rr = C4 * xx + C3;
                rr = rr * xx + C2;
                rr = rr * xx + C1;
                rr = rr * xx + C0;
                pu.h[pr] = rr;
            }
            const half8 pf = pu.v;
            o0a[t] = __builtin_amdgcn_mfma_f32_16x16x32_f16(vA0, pf, o0a[t], 0, 0, 0);
            o1a[t] = __builtin_amdgcn_mfma_f32_16x16x32_f16(vA1, pf, o1a[t], 0, 0, 0);
            la[t]  = __builtin_amdgcn_mfma_f32_16x16x32_f16(ones_h, pf, la[t], 0, 0, 0);
        }

        // ---- subtile B (keys +32..63) ----
#pragma unroll
        for (int t = 0; t < 2; ++t) {
            s0[t] = __builtin_amdgcn_mfma_f32_16x16x32_bf16(kB0, qf[t], z, 0, 0, 0);
            s1[t] = __builtin_amdgcn_mfma_f32_16x16x32_bf16(kB1, qf[t], z, 0, 0, 0);
        }
#pragma unroll
        for (int t = 0; t < 2; ++t) {
            float x0[4], x1[4];
#pragma unroll
            for (int r = 0; r < 4; ++r) {
                x0[r] = (mw[t].y & bitL[r]) ? s0[t][r] : 0.0f;
                x1[r] = (mw[t].y & bitH[r]) ? s1[t][r] : 0.0f;
            }
            union { half2v h[4]; half8 v; } pu;
#pragma unroll
            for (int pr = 0; pr < 4; ++pr) {
                const half2v xx = (pr < 2) ? cvt2h(x0[pr * 2], x0[pr * 2 + 1])
                                           : cvt2h(x1[(pr - 2) * 2], x1[(pr - 2) * 2 + 1]);
                half2v rr = C4 * xx + C3;
                rr = rr * xx + C2;
                rr = rr * xx + C1;
                rr = rr * xx + C0;
                pu.h[pr] = rr;
            }
            const half8 pf = pu.v;
            o0a[t] = __builtin_amdgcn_mfma_f32_16x16x32_f16(vB0, pf, o0a[t], 0, 0, 0);
            o1a[t] = __builtin_amdgcn_mfma_f32_16x16x32_f16(vB1, pf, o1a[t], 0, 0, 0);
            la[t]  = __builtin_amdgcn_mfma_f32_16x16x32_f16(ones_h, pf, la[t], 0, 0, 0);
        }

        Kp  += 64 * DH_;
        Vp0 += 64;
        Vp1 += 64;
#pragma unroll
        for (int t = 0; t < 2; ++t) mp[t] += 2;
    }

    _Float16* Ob = Opart + (size_t)part * B_ * S_ * E_;
    float* lp = lpart + (size_t)part * B_ * H_ * S_ + (size_t)bh * S_;
#pragma unroll
    for (int t = 0; t < 2; ++t) {
        union { half2v h[2]; uint2 u; } u0, u1;
        u0.h[0] = cvt2h(o0a[t][0], o0a[t][1]);
        u0.h[1] = cvt2h(o0a[t][2], o0a[t][3]);
        u1.h[0] = cvt2h(o1a[t][0], o1a[t][1]);
        u1.h[1] = cvt2h(o1a[t][2], o1a[t][3]);
        _Float16* orow = Ob + ((size_t)b * S_ + q0 + t * 16 + col) * E_ + h * DH_;
        *reinterpret_cast<uint2*>(orow + quad * 4)      = u0.u;
        *reinterpret_cast<uint2*>(orow + 16 + quad * 4) = u1.u;
        if (quad == 0) lp[q0 + t * 16 + col] = la[t][0];
    }
}

// ---------------------------------------------------------------------------
// Kernel 3: output projection, fp16 operands + f16 MFMA, split-K combine via
// packed v_pk_add_f16 + v_pk_mul_f16 by rcp(sum l).
// Wave: 16 m x 64 n. grid = (M/16, 768/256), block = 256.
// ---------------------------------------------------------------------------
template <int PARTS>
__global__ __launch_bounds__(256) void proj_kernel(
    const _Float16* __restrict__ Opart,       // [PARTS][4096][768] fp16
    const float* __restrict__ lpart,          // [PARTS][B*H][S]
    const _Float16* __restrict__ Wob,         // [768][768] fp16
    const float* __restrict__ bo,             // [768] fp32
    float* __restrict__ out)                  // [4096][768] fp32
{
    const int wave = threadIdx.x >> 6;
    const int lane = threadIdx.x & 63;
    const int col  = lane & 15;
    const int quad = lane >> 4;
    const int m0   = blockIdx.x * 16;
    const int n0   = blockIdx.y * 256 + wave * 64;

    const int m = m0 + col;
    const int b = m / S_;
    const int s = m - b * S_;
    const float* lpb = lpart + (size_t)(b * H_) * S_ + s;

    f32x4 acc[4] = {{0.f,0.f,0.f,0.f},{0.f,0.f,0.f,0.f},
                    {0.f,0.f,0.f,0.f},{0.f,0.f,0.f,0.f}};
    for (int k0 = 0; k0 < E_; k0 += 32) {
        const int h = k0 >> 5;
        const size_t aofs = (size_t)m * E_ + k0 + quad * 8;

        float l = 0.f;
#pragma unroll
        for (int pp = 0; pp < PARTS; ++pp)
            l += lpb[(size_t)pp * B_ * H_ * S_ + (size_t)h * S_];
        const float linv = __builtin_amdgcn_rcpf(l);
        const half2v lv = cvt2h(linv, linv);

        union UA { uint4 u; half2v h[4]; half8 v; } ua;
        ua.u = *reinterpret_cast<const uint4*>(Opart + aofs);
#pragma unroll
        for (int pp = 1; pp < PARTS; ++pp) {
            union UA ub;
            ub.u = *reinterpret_cast<const uint4*>(
                Opart + (size_t)pp * B_ * S_ * E_ + aofs);
#pragma unroll
            for (int i = 0; i < 4; ++i) ua.h[i] += ub.h[i];
        }
#pragma unroll
        for (int i = 0; i < 4; ++i) ua.h[i] *= lv;
        const half8 af = ua.v;

#pragma unroll
        for (int j = 0; j < 4; ++j) {
            union UA wb;
            wb.u = *reinterpret_cast<const uint4*>(
                Wob + (size_t)(n0 + j * 16 + col) * E_ + k0 + quad * 8);
            acc[j] = __builtin_amdgcn_mfma_f32_16x16x32_f16(af, wb.v, acc[j], 0, 0, 0);
        }
    }
#pragma unroll
    for (int j = 0; j < 4; ++j) {
        const int n = n0 + j * 16 + col;
        const float bias = bo[n];
#pragma unroll
        for (int r = 0; r < 4; ++r) {
            const int mm = m0 + quad * 4 + r;
            out[(size_t)mm * E_ + n] = acc[j][r] + bias;
        }
    }
}

// ---------------------------------------------------------------------------
extern "C" void kernel_launch(void* const* d_in, const int* in_sizes, int n_in,
                              void* d_out, int out_size, void* d_ws, size_t ws_size,
                              hipStream_t stream)
{
    const float* emb = (const float*)d_in[0];
    const int*   msk = (const int*)d_in[1];
    const float* Wq  = (const float*)d_in[2];
    const float* Wk  = (const float*)d_in[3];
    const float* Wv  = (const float*)d_in[4];
    const float* Wo  = (const float*)d_in[5];
    const float* bo  = (const float*)d_in[6];
    float* out = (float*)d_out;

    const size_t nqkv = (size_t)B_ * H_ * S_ * DH_;   // 3,145,728 (= B*S*E)
    char* p = (char*)d_ws;
    __hip_bfloat16* Q    = (__hip_bfloat16*)p;  p += nqkv * 2;
    __hip_bfloat16* Kp   = (__hip_bfloat16*)p;  p += nqkv * 2;
    _Float16*      Vt    = (_Float16*)p;        p += nqkv * 2;
    unsigned int*  mbits = (unsigned int*)p;    p += (size_t)B_ * S_ * SW_ * 4;
    _Float16*      Wob   = (_Float16*)p;        p += (size_t)E_ * E_ * 2;
    _Float16*      Op    = (_Float16*)p;                      // [parts][B][S][E]
    const size_t base = (size_t)(p - (char*)d_ws);

    int parts = 1;
    {
        const size_t need = base + (size_t)2 * nqkv * 2
                          + (size_t)2 * B_ * H_ * S_ * 4;
        if (ws_size >= need) parts = 2;
    }
    float* lpart = (float*)(Op + (size_t)parts * nqkv);

    prep_qkv_kernel<<<NB_QKV + NB_MASK + NB_WO, 256, 0, stream>>>(
        emb, msk, Wo, Wq, Wk, Wv, Q, Kp, Vt, mbits, Wob);
    attn_kernel<<<3072 * parts, 64, 0, stream>>>(
        Q, Kp, Vt, mbits, Op, lpart, parts);
    if (parts == 2)
        proj_kernel<2><<<dim3((B_ * S_) / 16, E_ / 256), 256, 0, stream>>>(
            Op, lpart, Wob, bo, out);
    else
        proj_kernel<1><<<dim3((B_ * S_) / 16, E_ / 256), 256, 0, stream>>>(
            Op, lpart, Wob, bo, out);
}

// Round 18
// 231.517 us; speedup vs baseline: 1.1100x; 1.1100x over previous
//
#include <hip/hip_runtime.h>
#include <hip/hip_bf16.h>

#define B_  2
#define S_  2048
#define H_  24
#define DH_ 32
#define E_  768
#define SW_ (S_/32)   // mask words per row = 64

#define NB_QKV  ((S_/64)*(B_*H_))      // 1536 blocks (qkv part, dispatched first)
#define NB_MASK ((B_*S_*S_)/256)       // 32768 blocks
#define NB_WO   ((E_*E_)/1024)         // 576 blocks

typedef __attribute__((ext_vector_type(8))) short short8;   // 8 x bf16 bits
typedef __attribute__((ext_vector_type(4))) float f32x4;
typedef _Float16 half8  __attribute__((ext_vector_type(8)));
typedef _Float16 half2v __attribute__((ext_vector_type(2)));
typedef __fp16   fp16x2 __attribute__((ext_vector_type(2)));   // cvt_pkrtz return type

// fp32 pair -> packed fp16 (one v_cvt_pkrtz_f16_f32), as _Float16 vector
static __device__ __forceinline__ half2v cvt2h(float a, float b) {
    fp16x2 t = __builtin_amdgcn_cvt_pkrtz(a, b);
    return __builtin_bit_cast(half2v, t);
}

// 4 floats -> 4 bf16 packed in 8B
static __device__ __forceinline__ short4 pack4(float a, float b, float c, float d) {
    union { __hip_bfloat162 h[2]; short4 s; } u;
    u.h[0] = __float22bfloat162_rn(make_float2(a, b));
    u.h[1] = __float22bfloat162_rn(make_float2(c, d));
    return u.s;
}
static __device__ __forceinline__ short8 pack8f(const float* a, const float* b) {
    union { __hip_bfloat162 h[4]; short8 s; } u;
    u.h[0] = __float22bfloat162_rn(make_float2(a[0], a[1]));
    u.h[1] = __float22bfloat162_rn(make_float2(a[2], a[3]));
    u.h[2] = __float22bfloat162_rn(make_float2(b[0], b[1]));
    u.h[3] = __float22bfloat162_rn(make_float2(b[2], b[3]));
    return u.s;
}
static __device__ __forceinline__ short8 pack8(float4 a, float4 b) {
    union { __hip_bfloat162 h[4]; short8 s; } u;
    u.h[0] = __float22bfloat162_rn(make_float2(a.x, a.y));
    u.h[1] = __float22bfloat162_rn(make_float2(a.z, a.w));
    u.h[2] = __float22bfloat162_rn(make_float2(b.x, b.y));
    u.h[3] = __float22bfloat162_rn(make_float2(b.z, b.w));
    return u.s;
}
// weight fragment straight from fp32 W[h-base][d][e]: F[j] = W[(quad*8+j)*32+eo]
static __device__ __forceinline__ short8 wfrag(const float* __restrict__ Wb,
                                               int quad, int eo) {
    float w[8];
#pragma unroll
    for (int j = 0; j < 8; ++j) w[j] = Wb[(quad * 8 + j) * 32 + eo];
    return pack8f(w, w + 4);
}

// Q pre-scaled by (1/sqrt(32))*log2(e): MFMA scores land in the exp2 domain.
// Masked branch selects x=0 BEFORE the poly; poly(0) = 1.0 exactly =
// exp(-1e-6) at working precision.
#define QSCALE  0.25503487f

// ---------------------------------------------------------------------------
// Kernel 0: FUSED prep + qkv (mutually independent parts, one launch).
// ---------------------------------------------------------------------------
__global__ __launch_bounds__(256) void prep_qkv_kernel(
    const float* __restrict__ x, const int* __restrict__ mask,
    const float* __restrict__ Wo,
    const float* __restrict__ Wq, const float* __restrict__ Wk,
    const float* __restrict__ Wv,
    __hip_bfloat16* __restrict__ Qo,
    __hip_bfloat16* __restrict__ Ko,      // permuted-key layout, bf16
    _Float16* __restrict__ Vto,           // fp16 (PV runs on f16 MFMA)
    unsigned int* __restrict__ mbits, _Float16* __restrict__ Wob)
{
    const int bx = blockIdx.x;
    if (bx < NB_QKV) {
        // ---- QKV: 16 s-rows/wave, 6 MFMAs. K stored PERMUTED within each
        // 32-key tile: key k=8q+4u+i -> slot (u<<4)|(q*4+i) so attn's score
        // MFMAs produce P directly in PV B-operand register layout. ----
        const int bh   = bx >> 5;            // [0,48)
        const int b    = bh / H_;
        const int h    = bh - b * H_;
        const int wave = threadIdx.x >> 6;
        const int lane = threadIdx.x & 63;
        const int col  = lane & 15;
        const int quad = lane >> 4;
        const int sw   = (bx & 31) * 64 + wave * 16;
        const int s    = sw + col;

        const float* xp = x + ((size_t)b * S_ + s) * E_ + h * DH_ + quad * 8;
        const float4 xa = *reinterpret_cast<const float4*>(xp);
        const float4 xb = *reinterpret_cast<const float4*>(xp + 4);
        const short8 xf = pack8(xa, xb);

        const int wb = h * DH_ * DH_;
        const short8 aQ0 = wfrag(Wq + wb, quad, col);
        const short8 aQ1 = wfrag(Wq + wb, quad, col + 16);
        const short8 aK0 = wfrag(Wk + wb, quad, col);
        const short8 aK1 = wfrag(Wk + wb, quad, col + 16);
        const short8 bV0 = wfrag(Wv + wb, quad, col);
        const short8 bV1 = wfrag(Wv + wb, quad, col + 16);

        const f32x4 z = {0.f, 0.f, 0.f, 0.f};
        const f32x4 qt0 = __builtin_amdgcn_mfma_f32_16x16x32_bf16(aQ0, xf, z, 0, 0, 0);
        const f32x4 qt1 = __builtin_amdgcn_mfma_f32_16x16x32_bf16(aQ1, xf, z, 0, 0, 0);
        const f32x4 kt0 = __builtin_amdgcn_mfma_f32_16x16x32_bf16(aK0, xf, z, 0, 0, 0);
        const f32x4 kt1 = __builtin_amdgcn_mfma_f32_16x16x32_bf16(aK1, xf, z, 0, 0, 0);
        const f32x4 vv0 = __builtin_amdgcn_mfma_f32_16x16x32_bf16(xf, bV0, z, 0, 0, 0);
        const f32x4 vv1 = __builtin_amdgcn_mfma_f32_16x16x32_bf16(xf, bV1, z, 0, 0, 0);

        __hip_bfloat16* qrow = Qo + ((size_t)bh * S_ + s) * DH_;
        *reinterpret_cast<short4*>(qrow + quad * 4) =
            pack4(qt0[0] * QSCALE, qt0[1] * QSCALE, qt0[2] * QSCALE, qt0[3] * QSCALE);
        *reinterpret_cast<short4*>(qrow + 16 + quad * 4) =
            pack4(qt1[0] * QSCALE, qt1[1] * QSCALE, qt1[2] * QSCALE, qt1[3] * QSCALE);

        const int t32  = s & 31;
        const int slot = (s & ~31) | (((t32 >> 2) & 1) << 4)
                       | (((t32 >> 3) << 2) | (t32 & 3));
        __hip_bfloat16* krow = Ko + ((size_t)bh * S_ + slot) * DH_;
        *reinterpret_cast<short4*>(krow + quad * 4)      = pack4(kt0[0], kt0[1], kt0[2], kt0[3]);
        *reinterpret_cast<short4*>(krow + 16 + quad * 4) = pack4(kt1[0], kt1[1], kt1[2], kt1[3]);

        const int sb = sw + quad * 4;
        union { half2v h[2]; uint2 u; } v0u, v1u;
        v0u.h[0] = cvt2h(vv0[0], vv0[1]); v0u.h[1] = cvt2h(vv0[2], vv0[3]);
        v1u.h[0] = cvt2h(vv1[0], vv1[1]); v1u.h[1] = cvt2h(vv1[2], vv1[3]);
        *reinterpret_cast<uint2*>(Vto + ((size_t)bh * DH_ + col) * S_ + sb)      = v0u.u;
        *reinterpret_cast<uint2*>(Vto + ((size_t)bh * DH_ + 16 + col) * S_ + sb) = v1u.u;
    } else if (bx < NB_QKV + NB_MASK) {
        const int idx  = (bx - NB_QKV) * 256 + threadIdx.x;
        const int lane = threadIdx.x & 63;
        const unsigned long long bal = __ballot(mask[idx] != 0);
        if (lane == 0) {
            uint2 w;
            w.x = (unsigned int)(bal & 0xffffffffull);
            w.y = (unsigned int)(bal >> 32);
            *reinterpret_cast<uint2*>(mbits + (idx >> 5)) = w;
        }
    } else {
        const int i = ((bx - NB_QKV - NB_MASK) * 256 + threadIdx.x) * 4;
        const float4 w = *reinterpret_cast<const float4*>(Wo + i);
        union { half2v h[2]; uint2 u; } uu;
        uu.h[0] = cvt2h(w.x, w.y);
        uu.h[1] = cvt2h(w.z, w.w);
        *reinterpret_cast<uint2*>(Wob + i) = uu.u;
    }
}

// ---------------------------------------------------------------------------
// Kernel 2: fused attention v14 (BEST CONFIG, R16: attn 77us) — poly-exp on
// the packed-fp16 pipe, 64 q-rows/wave (max K/V amortization — R17 proved
// halving the tile regresses 31% via doubled VMEM issue), 64 keys/iter,
// register P, l via ones-MFMA, XCD swizzle, single-wave blocks.
// grid = 1536*parts, block = 64.
// ---------------------------------------------------------------------------
__global__ __launch_bounds__(64) void attn_kernel(
    const __hip_bfloat16* __restrict__ Q,     // [B*H][S][DH] (pre-scaled)
    const __hip_bfloat16* __restrict__ K,     // [B*H][S][DH] permuted tiles
    const _Float16* __restrict__ Vt,          // [B*H][DH][S] fp16
    const unsigned int* __restrict__ mbits,   // [B][S][S/32]
    _Float16* __restrict__ Opart,             // [parts][B][S][E] unnormalized
    float* __restrict__ lpart,                // [parts][B*H][S]
    int parts)
{
    const int bid  = blockIdx.x;
    const int xcd  = bid & 7;
    const int t_   = bid >> 3;                 // [0, 6*32*parts)
    const int bh   = xcd * 6 + (t_ % 6);
    const int rest = t_ / 6;                   // [0, 32*parts)
    const int qsub = rest & 31;
    const int part = rest >> 5;

    const int b    = bh / H_;
    const int h    = bh - b * H_;
    const int niter = S_ / (64 * parts);
    const int kbeg  = part * (S_ / parts);
    const int lane = threadIdx.x & 63;
    const int col  = lane & 15;
    const int quad = lane >> 4;
    const int q0   = qsub * 64;

    const __hip_bfloat16* Qbh = Q  + (size_t)bh * S_ * DH_;
    const __hip_bfloat16* Kbh = K  + (size_t)bh * S_ * DH_;
    const _Float16*       Vbh = Vt + (size_t)bh * DH_ * S_;

    short8 qf[4];
#pragma unroll
    for (int t = 0; t < 4; ++t)
        qf[t] = *reinterpret_cast<const short8*>(
            Qbh + (size_t)(q0 + t * 16 + col) * DH_ + quad * 8);

    const __hip_bfloat16* Kp  = Kbh + (size_t)(kbeg + col) * DH_ + quad * 8;
    const _Float16*       Vp0 = Vbh + (size_t)col * S_ + kbeg + quad * 8;
    const _Float16*       Vp1 = Vbh + (size_t)(16 + col) * S_ + kbeg + quad * 8;
    const unsigned int* mbb = mbits + (size_t)b * S_ * SW_ + (kbeg >> 5);
    const unsigned int* mp[4];
#pragma unroll
    for (int t = 0; t < 4; ++t)
        mp[t] = mbb + (size_t)(q0 + t * 16 + col) * SW_;

    // per-lane AND-bitmasks
    unsigned bitL[4], bitH[4];
#pragma unroll
    for (int r = 0; r < 4; ++r) {
        bitL[r] = 1u << (quad * 8 + r);
        bitH[r] = 1u << (quad * 8 + 4 + r);
    }

    // 2^x Taylor-4 coefficients, packed fp16
    const half2v C4 = cvt2h(0.0096181f, 0.0096181f);
    const half2v C3 = cvt2h(0.0555041f, 0.0555041f);
    const half2v C2 = cvt2h(0.2402265f, 0.2402265f);
    const half2v C1 = cvt2h(0.6931472f, 0.6931472f);
    const half2v C0 = cvt2h(1.0f, 1.0f);

    union { uint4 u; half8 v; } onesu;
    onesu.u = make_uint4(0x3C003C00u, 0x3C003C00u, 0x3C003C00u, 0x3C003C00u);
    const half8 ones_h = onesu.v;

    f32x4 o0a[4], o1a[4], la[4];
#pragma unroll
    for (int t = 0; t < 4; ++t) {
        o0a[t] = (f32x4){0.f,0.f,0.f,0.f};
        o1a[t] = (f32x4){0.f,0.f,0.f,0.f};
        la[t]  = (f32x4){0.f,0.f,0.f,0.f};
    }

    for (int it = 0; it < niter; ++it) {
        uint2 mw[4];
#pragma unroll
        for (int t = 0; t < 4; ++t)
            mw[t] = *reinterpret_cast<const uint2*>(mp[t]);

        const short8 kA0 = *reinterpret_cast<const short8*>(Kp);
        const short8 kA1 = *reinterpret_cast<const short8*>(Kp + 16 * DH_);
        const half8  vA0 = *reinterpret_cast<const half8*>(Vp0);
        const half8  vA1 = *reinterpret_cast<const half8*>(Vp1);
        const short8 kB0 = *reinterpret_cast<const short8*>(Kp + 32 * DH_);
        const short8 kB1 = *reinterpret_cast<const short8*>(Kp + 48 * DH_);
        const half8  vB0 = *reinterpret_cast<const half8*>(Vp0 + 32);
        const half8  vB1 = *reinterpret_cast<const half8*>(Vp1 + 32);

        const f32x4 z = {0.f, 0.f, 0.f, 0.f};

        // ---- subtile A (keys +0..31) ----
        f32x4 s0[4], s1[4];
#pragma unroll
        for (int t = 0; t < 4; ++t) {
            s0[t] = __builtin_amdgcn_mfma_f32_16x16x32_bf16(kA0, qf[t], z, 0, 0, 0);
            s1[t] = __builtin_amdgcn_mfma_f32_16x16x32_bf16(kA1, qf[t], z, 0, 0, 0);
        }
#pragma unroll
        for (int t = 0; t < 4; ++t) {
            float x0[4], x1[4];
#pragma unroll
            for (int r = 0; r < 4; ++r) {
                x0[r] = (mw[t].x & bitL[r]) ? s0[t][r] : 0.0f;
                x1[r] = (mw[t].x & bitH[r]) ? s1[t][r] : 0.0f;
            }
            union { half2v h[4]; half8 v; } pu;
#pragma unroll
            for (int pr = 0; pr < 4; ++pr) {
                const half2v xx = (pr < 2) ? cvt2h(x0[pr * 2], x0[pr * 2 + 1])
                                           : cvt2h(x1[(pr - 2) * 2], x1[(pr - 2) * 2 + 1]);
                half2v rr = C4 * xx + C3;
                rr = rr * xx + C2;
                rr = rr * xx + C1;
                rr = rr * xx + C0;
                pu.h[pr] = rr;
            }
            const half8 pf = pu.v;
            o0a[t] = __builtin_amdgcn_mfma_f32_16x16x32_f16(vA0, pf, o0a[t], 0, 0, 0);
            o1a[t] = __builtin_amdgcn_mfma_f32_16x16x32_f16(vA1, pf, o1a[t], 0, 0, 0);
            la[t]  = __builtin_amdgcn_mfma_f32_16x16x32_f16(ones_h, pf, la[t], 0, 0, 0);
        }

        // ---- subtile B (keys +32..63) ----
#pragma unroll
        for (int t = 0; t < 4; ++t) {
            s0[t] = __builtin_amdgcn_mfma_f32_16x16x32_bf16(kB0, qf[t], z, 0, 0, 0);
            s1[t] = __builtin_amdgcn_mfma_f32_16x16x32_bf16(kB1, qf[t], z, 0, 0, 0);
        }
#pragma unroll
        for (int t = 0; t < 4; ++t) {
            float x0[4], x1[4];
#pragma unroll
            for (int r = 0; r < 4; ++r) {
                x0[r] = (mw[t].y & bitL[r]) ? s0[t][r] : 0.0f;
                x1[r] = (mw[t].y & bitH[r]) ? s1[t][r] : 0.0f;
            }
            union { half2v h[4]; half8 v; } pu;
#pragma unroll
            for (int pr = 0; pr < 4; ++pr) {
                const half2v xx = (pr < 2) ? cvt2h(x0[pr * 2], x0[pr * 2 + 1])
                                           : cvt2h(x1[(pr - 2) * 2], x1[(pr - 2) * 2 + 1]);
                half2v rr = C4 * xx + C3;
                rr = rr * xx + C2;
                rr = rr * xx + C1;
                rr = rr * xx + C0;
                pu.h[pr] = rr;
            }
            const half8 pf = pu.v;
            o0a[t] = __builtin_amdgcn_mfma_f32_16x16x32_f16(vB0, pf, o0a[t], 0, 0, 0);
            o1a[t] = __builtin_amdgcn_mfma_f32_16x16x32_f16(vB1, pf, o1a[t], 0, 0, 0);
            la[t]  = __builtin_amdgcn_mfma_f32_16x16x32_f16(ones_h, pf, la[t], 0, 0, 0);
        }

        Kp  += 64 * DH_;
        Vp0 += 64;
        Vp1 += 64;
#pragma unroll
        for (int t = 0; t < 4; ++t) mp[t] += 2;
    }

    _Float16* Ob = Opart + (size_t)part * B_ * S_ * E_;
    float* lp = lpart + (size_t)part * B_ * H_ * S_ + (size_t)bh * S_;
#pragma unroll
    for (int t = 0; t < 4; ++t) {
        union { half2v h[2]; uint2 u; } u0, u1;
        u0.h[0] = cvt2h(o0a[t][0], o0a[t][1]);
        u0.h[1] = cvt2h(o0a[t][2], o0a[t][3]);
        u1.h[0] = cvt2h(o1a[t][0], o1a[t][1]);
        u1.h[1] = cvt2h(o1a[t][2], o1a[t][3]);
        _Float16* orow = Ob + ((size_t)b * S_ + q0 + t * 16 + col) * E_ + h * DH_;
        *reinterpret_cast<uint2*>(orow + quad * 4)      = u0.u;
        *reinterpret_cast<uint2*>(orow + 16 + quad * 4) = u1.u;
        if (quad == 0) lp[q0 + t * 16 + col] = la[t][0];
    }
}

// ---------------------------------------------------------------------------
// Kernel 3: output projection, fp16 operands + f16 MFMA, split-K combine via
// packed v_pk_add_f16 + v_pk_mul_f16 by rcp(sum l).
// Wave: 16 m x 64 n. grid = (M/16, 768/256), block = 256.
// ---------------------------------------------------------------------------
template <int PARTS>
__global__ __launch_bounds__(256) void proj_kernel(
    const _Float16* __restrict__ Opart,       // [PARTS][4096][768] fp16
    const float* __restrict__ lpart,          // [PARTS][B*H][S]
    const _Float16* __restrict__ Wob,         // [768][768] fp16
    const float* __restrict__ bo,             // [768] fp32
    float* __restrict__ out)                  // [4096][768] fp32
{
    const int wave = threadIdx.x >> 6;
    const int lane = threadIdx.x & 63;
    const int col  = lane & 15;
    const int quad = lane >> 4;
    const int m0   = blockIdx.x * 16;
    const int n0   = blockIdx.y * 256 + wave * 64;

    const int m = m0 + col;
    const int b = m / S_;
    const int s = m - b * S_;
    const float* lpb = lpart + (size_t)(b * H_) * S_ + s;

    f32x4 acc[4] = {{0.f,0.f,0.f,0.f},{0.f,0.f,0.f,0.f},
                    {0.f,0.f,0.f,0.f},{0.f,0.f,0.f,0.f}};
    for (int k0 = 0; k0 < E_; k0 += 32) {
        const int h = k0 >> 5;
        const size_t aofs = (size_t)m * E_ + k0 + quad * 8;

        float l = 0.f;
#pragma unroll
        for (int pp = 0; pp < PARTS; ++pp)
            l += lpb[(size_t)pp * B_ * H_ * S_ + (size_t)h * S_];
        const float linv = __builtin_amdgcn_rcpf(l);
        const half2v lv = cvt2h(linv, linv);

        union UA { uint4 u; half2v h[4]; half8 v; } ua;
        ua.u = *reinterpret_cast<const uint4*>(Opart + aofs);
#pragma unroll
        for (int pp = 1; pp < PARTS; ++pp) {
            union UA ub;
            ub.u = *reinterpret_cast<const uint4*>(
                Opart + (size_t)pp * B_ * S_ * E_ + aofs);
#pragma unroll
            for (int i = 0; i < 4; ++i) ua.h[i] += ub.h[i];
        }
#pragma unroll
        for (int i = 0; i < 4; ++i) ua.h[i] *= lv;
        const half8 af = ua.v;

#pragma unroll
        for (int j = 0; j < 4; ++j) {
            union UA wb;
            wb.u = *reinterpret_cast<const uint4*>(
                Wob + (size_t)(n0 + j * 16 + col) * E_ + k0 + quad * 8);
            acc[j] = __builtin_amdgcn_mfma_f32_16x16x32_f16(af, wb.v, acc[j], 0, 0, 0);
        }
    }
#pragma unroll
    for (int j = 0; j < 4; ++j) {
        const int n = n0 + j * 16 + col;
        const float bias = bo[n];
#pragma unroll
        for (int r = 0; r < 4; ++r) {
            const int mm = m0 + quad * 4 + r;
            out[(size_t)mm * E_ + n] = acc[j][r] + bias;
        }
    }
}

// ---------------------------------------------------------------------------
extern "C" void kernel_launch(void* const* d_in, const int* in_sizes, int n_in,
                              void* d_out, int out_size, void* d_ws, size_t ws_size,
                              hipStream_t stream)
{
    const float* emb = (const float*)d_in[0];
    const int*   msk = (const int*)d_in[1];
    const float* Wq  = (const float*)d_in[2];
    const float* Wk  = (const float*)d_in[3];
    const float* Wv  = (const float*)d_in[4];
    const float* Wo  = (const float*)d_in[5];
    const float* bo  = (const float*)d_in[6];
    float* out = (float*)d_out;

    const size_t nqkv = (size_t)B_ * H_ * S_ * DH_;   // 3,145,728 (= B*S*E)
    char* p = (char*)d_ws;
    __hip_bfloat16* Q    = (__hip_bfloat16*)p;  p += nqkv * 2;
    __hip_bfloat16* Kp   = (__hip_bfloat16*)p;  p += nqkv * 2;
    _Float16*      Vt    = (_Float16*)p;        p += nqkv * 2;
    unsigned int*  mbits = (unsigned int*)p;    p += (size_t)B_ * S_ * SW_ * 4;
    _Float16*      Wob   = (_Float16*)p;        p += (size_t)E_ * E_ * 2;
    _Float16*      Op    = (_Float16*)p;                      // [parts][B][S][E]
    const size_t base = (size_t)(p - (char*)d_ws);

    // parts = 2 (R9/R14: 4 is attn-neutral and costs proj time)
    int parts = 1;
    {
        const size_t need = base + (size_t)2 * nqkv * 2
                          + (size_t)2 * B_ * H_ * S_ * 4;
        if (ws_size >= need) parts = 2;
    }
    float* lpart = (float*)(Op + (size_t)parts * nqkv);

    prep_qkv_kernel<<<NB_QKV + NB_MASK + NB_WO, 256, 0, stream>>>(
        emb, msk, Wo, Wq, Wk, Wv, Q, Kp, Vt, mbits, Wob);
    attn_kernel<<<1536 * parts, 64, 0, stream>>>(
        Q, Kp, Vt, mbits, Op, lpart, parts);
    if (parts == 2)
        proj_kernel<2><<<dim3((B_ * S_) / 16, E_ / 256), 256, 0, stream>>>(
            Op, lpart, Wob, bo, out);
    else
        proj_kernel<1><<<dim3((B_ * S_) / 16, E_ / 256), 256, 0, stream>>>(
            Op, lpart, Wob, bo, out);
}